// Round 14
// baseline (181.528 us; speedup 1.0000x reference)
//
#include <hip/hip_runtime.h>

#define S_LEN 4096
#define NH 16
#define DH 64
#define NE 1024

typedef __bf16 bf16_t;
typedef __bf16 bf16x8 __attribute__((ext_vector_type(8)));
typedef __bf16 bf16x4 __attribute__((ext_vector_type(4)));
typedef __bf16 bf16x2 __attribute__((ext_vector_type(2)));
typedef float  f32x4  __attribute__((ext_vector_type(4)));

#define QSCALE 0.180336879f  // 0.125 * log2(e): softmax in exp2 domain

// ---------------------------------------------------------------------------
// Fused pack kernel (unchanged). Blocks [0,4096): q,k -> head-major bf16
// (q pre-scaled QSCALE) + W -> bf16. Blocks [4096,5120): V -> vt[h][d][t']
// transpose with the within-64 key permutation (vt[pos] = V[ip(pos)]) so
// attn's PV B-fragment is one contiguous b128. Lanes write CONTIGUOUS vt
// addresses, read inverse-permuted LDS entries.
// ---------------------------------------------------------------------------
__global__ __launch_bounds__(256) void pack_all(const float* __restrict__ q,
                                                const float* __restrict__ k,
                                                const float* __restrict__ w,
                                                const float* __restrict__ v,
                                                bf16_t* __restrict__ qb,
                                                bf16_t* __restrict__ kb,
                                                bf16_t* __restrict__ wb,
                                                bf16_t* __restrict__ vt) {
    __shared__ bf16_t tile[64][65];
    const int bid = blockIdx.x;
    if (bid < 4096) {
        const int tid = bid * 256 + threadIdx.x;
        const int e = tid * 4;
        const int s = e >> 10;
        const int c = e & (NE - 1);
        const int h = c >> 6;
        const int d = c & (DH - 1);
        const int o = (h * S_LEN + s) * DH + d;
        float4 qv = *(const float4*)(q + e);
        float4 kv = *(const float4*)(k + e);
        bf16x4 qo, ko;
        qo[0] = (bf16_t)(qv.x * QSCALE); qo[1] = (bf16_t)(qv.y * QSCALE);
        qo[2] = (bf16_t)(qv.z * QSCALE); qo[3] = (bf16_t)(qv.w * QSCALE);
        ko[0] = (bf16_t)kv.x; ko[1] = (bf16_t)kv.y; ko[2] = (bf16_t)kv.z; ko[3] = (bf16_t)kv.w;
        *(bf16x4*)(qb + o) = qo;
        *(bf16x4*)(kb + o) = ko;
        if (tid < (NE * NE / 4)) {
            float4 wv = *(const float4*)(w + tid * 4);
            bf16x4 wo;
            wo[0] = (bf16_t)wv.x; wo[1] = (bf16_t)wv.y; wo[2] = (bf16_t)wv.z; wo[3] = (bf16_t)wv.w;
            *(bf16x4*)(wb + tid * 4) = wo;
        }
    } else {
        const int vb = bid - 4096;
        const int h  = vb >> 6;
        const int t0 = (vb & 63) * 64;
        const int r  = threadIdx.x >> 6;   // 0..3
        const int cl = threadIdx.x & 63;
#pragma unroll
        for (int rep = 0; rep < 16; ++rep) {
            int i = rep * 4 + r;
            tile[cl][i] = (bf16_t)v[(t0 + i) * NE + h * DH + cl];
        }
        __syncthreads();
        const int r2  = threadIdx.x >> 5;        // 0..7
        const int cl2 = (threadIdx.x & 31) * 2;  // 0..62 even
        // inverse key permutation: old = n5*32 + n2*16 + n4*8 + n3*4 + n1n0
        const int ip = (cl2 & 32) + ((cl2 >> 2) & 1) * 16 + ((cl2 >> 4) & 1) * 8 +
                       ((cl2 >> 3) & 1) * 4 + (cl2 & 3);
#pragma unroll
        for (int rep = 0; rep < 8; ++rep) {
            int d = rep * 8 + r2;
            bf16x2 out;
            out[0] = tile[d][ip];
            out[1] = tile[d][ip + 1];
            *(bf16x2*)(vt + (h * DH + d) * S_LEN + t0 + cl2) = out;
        }
    }
}

// ---------------------------------------------------------------------------
// Flash attention v19 (round-12/13 verbatim, 63 us measured): 4-slot LDS
// ring (1 barrier / 2 tiles), swapped QK^T (no P round-trip), pre-permuted
// V (single b128 PV B-frags), ones-MFMA row sums, raw v_exp_f32 softmax,
// hoisted per-chunk mask limit.
// ---------------------------------------------------------------------------
__global__ __launch_bounds__(512, 4) void attn(const bf16_t* __restrict__ qb,
                                               const bf16_t* __restrict__ kb,
                                               const bf16_t* __restrict__ vt,
                                               float* __restrict__ po,
                                               float* __restrict__ ls) {
    __shared__ __align__(16) bf16_t kbuf[4][64 * 72];
    __shared__ __align__(16) bf16_t vbuf[4][64 * 72];

    const int tid  = threadIdx.x;
    const int wave = tid >> 6;        // 0..7
    const int lane = tid & 63;
    const int l15  = lane & 15;
    const int quad = lane >> 4;
    const int h = blockIdx.x;
    const int x = blockIdx.y;

    const int sA = x;
    const int sB = 31 - x;
    const int n0 = x + 1;            // phase0 tile count
    const int b1 = sB + 1;           // phase1 first tile -> t0 base
    const int N  = 33;               // constant for all x

    const bf16_t* __restrict__ qh = qb + h * (S_LEN * DH);
    const bf16_t* __restrict__ kh = kb + h * (S_LEN * DH);
    const bf16_t* __restrict__ vh = vt + h * (DH * S_LEN);

    const int row0 = tid >> 3;        // 0..63
    const int tc8  = (tid & 7) * 8;   // 0..56
    const int stg  = row0 * 72 + tc8; // staging LDS offset (elements)
    const int frg  = l15 * 72 + quad * 8;  // fragment base offset (elements)

    f32x4 o_acc[4];
    f32x4 rs;                         // running row-sums via ones-MFMA
    bf16x8 qA[2];
    bf16x8 ones;
#pragma unroll
    for (int e = 0; e < 8; ++e) ones[e] = (bf16_t)1.0f;
    int s0 = sA * 128 + wave * 16;

    auto t0_of = [&](int j) { return (j < n0 ? j : b1 + (j - n0)) * 64; };

    auto load_q = [&](int s0_) {
#pragma unroll
        for (int dc = 0; dc < 2; ++dc)
            qA[dc] = *(const bf16x8*)(qh + (s0_ + l15) * DH + dc * 32 + quad * 8);
    };
    auto reset_acc = [&]() {
#pragma unroll
        for (int db = 0; db < 4; ++db) o_acc[db] = (f32x4){0.f, 0.f, 0.f, 0.f};
        rs = (f32x4){0.f, 0.f, 0.f, 0.f};
    };
    auto epilogue = [&](int s0_, int slot) {
        float* poz = po + (size_t)(slot * NH + h) * S_LEN * DH;
#pragma unroll
        for (int r = 0; r < 4; ++r)
#pragma unroll
            for (int db = 0; db < 4; ++db)
                poz[(s0_ + quad * 4 + r) * DH + db * 16 + l15] = o_acc[db][r];
        if (l15 == 0) {
            float* lsz = ls + (size_t)(slot * NH + h) * S_LEN;
#pragma unroll
            for (int r = 0; r < 4; ++r) lsz[s0_ + quad * 4 + r] = rs[r];
        }
    };

    load_q(s0);
    reset_acc();

    // prologue: stage tiles 0 and 1 into ring slots 0, 1
#pragma unroll
    for (int jj = 0; jj < 2; ++jj) {
        const int t0p = t0_of(jj);
        bf16x8 kr = *(const bf16x8*)(kh + (t0p + row0) * DH + tc8);
        bf16x8 vr = *(const bf16x8*)(vh + row0 * S_LEN + t0p + tc8);
        *(bf16x8*)(kbuf[jj] + stg) = kr;
        *(bf16x8*)(vbuf[jj] + stg) = vr;
    }
    __syncthreads();

    bf16x8 krn[2], vrn[2];            // prefetch regs for the next pair

#pragma unroll 2
    for (int j = 0; j < N; ++j) {
        if (j == n0) {  // phase switch (block-uniform)
            epilogue(s0, 0);
            s0 = sB * 128 + wave * 16;
            load_q(s0);
            reset_acc();
        }
        const int t0 = t0_of(j);
        const bf16_t* kb_ = kbuf[j & 3];
        const bf16_t* vb_ = vbuf[j & 3];

        if ((j & 1) == 0) {
            // pair start: issue global loads for tiles j+2, j+3 (uniform guards)
#pragma unroll
            for (int u = 0; u < 2; ++u) {
                const int jn = j + 2 + u;
                if (jn < N) {
                    const int tn = t0_of(jn);
                    krn[u] = *(const bf16x8*)(kh + (tn + row0) * DH + tc8);
                    vrn[u] = *(const bf16x8*)(vh + row0 * S_LEN + tn + tc8);
                }
            }
        }

        // wave-uniform: this tile contributes only if some key <= some query
        if (t0 <= s0 + 15) {
            // ---- swapped QK^T: A = K fragments, B = Q (in registers)
            f32x4 c_[4];
#pragma unroll
            for (int ch = 0; ch < 4; ++ch) {
                bf16x8 kB0 = *(const bf16x8*)(kb_ + frg + ch * (16 * 72));
                bf16x8 kB1 = *(const bf16x8*)(kb_ + frg + ch * (16 * 72) + 32);
                f32x4 zr = (f32x4){0.f, 0.f, 0.f, 0.f};
                zr = __builtin_amdgcn_mfma_f32_16x16x32_bf16(kB0, qA[0], zr, 0, 0, 0);
                zr = __builtin_amdgcn_mfma_f32_16x16x32_bf16(kB1, qA[1], zr, 0, 0, 0);
                c_[ch] = zr;
            }

            // ---- mask + exp2 + lane-local pack into PV A-fragments
            // lane holds S^T[key=t0+16ch+4quad+r][query=s0+l15].
            // Mask limit hoisted: element (ch,r) masked iff r > lim(ch).
            const int query = s0 + l15;
            float p[4][4];
#pragma unroll
            for (int ch = 0; ch < 4; ++ch) {
                if (t0 + ch * 16 <= s0 + 15) {       // wave-uniform chunk-live
                    const bool edge = (t0 + ch * 16 + 15 > s0);
                    const int lim = query - (t0 + ch * 16 + quad * 4);
#pragma unroll
                    for (int r = 0; r < 4; ++r) {
                        float cc = c_[ch][r];
                        if (edge && r > lim) cc = -INFINITY;
                        p[ch][r] = __builtin_amdgcn_exp2f(cc);
                    }
                } else {
#pragma unroll
                    for (int r = 0; r < 4; ++r) p[ch][r] = 0.0f;
                }
            }

            bf16x8 pA[2];
#pragma unroll
            for (int kc = 0; kc < 2; ++kc) {
                bf16x8 t;
                t[0] = (bf16_t)p[2 * kc][0];     t[1] = (bf16_t)p[2 * kc][1];
                t[2] = (bf16_t)p[2 * kc][2];     t[3] = (bf16_t)p[2 * kc][3];
                t[4] = (bf16_t)p[2 * kc + 1][0]; t[5] = (bf16_t)p[2 * kc + 1][1];
                t[6] = (bf16_t)p[2 * kc + 1][2]; t[7] = (bf16_t)p[2 * kc + 1][3];
                pA[kc] = t;
            }

            // ---- row-sums on the matrix pipe (replaces 16 VALU adds)
            rs = __builtin_amdgcn_mfma_f32_16x16x32_bf16(pA[0], ones, rs, 0, 0, 0);
            rs = __builtin_amdgcn_mfma_f32_16x16x32_bf16(pA[1], ones, rs, 0, 0, 0);

            // ---- PV: V pre-permuted -> single uniform b128 per fragment
#pragma unroll
            for (int db = 0; db < 4; ++db) {
#pragma unroll
                for (int kc = 0; kc < 2; ++kc) {
                    bf16x8 vB = *(const bf16x8*)(vb_ + frg + db * (16 * 72) + kc * 32);
                    o_acc[db] = __builtin_amdgcn_mfma_f32_16x16x32_bf16(pA[kc], vB, o_acc[db], 0, 0, 0);
                }
            }
        }

        if (j & 1) {
            // pair end: commit staged tiles j+1, j+2 to their ring slots,
            // then ONE barrier for the pair.
#pragma unroll
            for (int u = 0; u < 2; ++u) {
                const int jn = j + 1 + u;
                if (jn < N) {
                    *(bf16x8*)(kbuf[jn & 3] + stg) = krn[u];
                    *(bf16x8*)(vbuf[jn & 3] + stg) = vrn[u];
                }
            }
            __syncthreads();
        }
    }

    epilogue(s0, 1);
}

// ---------------------------------------------------------------------------
// Projection v11: Y[4096][1024] = combine(po,ls) @ W^T, fp32 out — the
// combine kernel is FUSED into the A-panel staging. Structural fact:
// k-chunk kt covers output cols [kt*64, kt*64+64) = exactly head h=kt, so
// the staged A-chunk is (po0[kt][row][d]+po1[kt][row][d]) * rcp(ls0+ls1),
// computed inline from fully-coalesced f32 po runs (256B/row) + broadcast
// ls scalars. Bit-identical to the old combine (same f32 add -> mul ->
// RNE-cvt order). Deletes: combine launch, its 40MB HBM pass, and the xb
// round-trip. po re-reads (16x logical across ny-blocks) are L3-absorbed
// (po = 32MB, freshly written). MFMA core, W staging, output indexing
// unchanged from the passing v10.
// ---------------------------------------------------------------------------
__global__ __launch_bounds__(512, 2) void proj(const float* __restrict__ po,
                                               const float* __restrict__ ls,
                                               const bf16_t* __restrict__ wb,
                                               float* __restrict__ y) {
    __shared__ __align__(16) bf16_t abuf[2][128 * 72];
    __shared__ __align__(16) bf16_t wbuf[2][64 * 72];
    const int tid  = threadIdx.x;
    const int wave = tid >> 6;        // 0..7
    const int lane = tid & 63;
    const int l15  = lane & 15;
    const int quad = lane >> 4;
    const int mb = blockIdx.x * 128;  // block row base
    const int m0 = mb + wave * 16;    // wave owns 16 rows
    const int n0 = blockIdx.y * 64;

    // A staging: 1024 slots of 8 elts; thread covers slots tid, tid+512
    const int rowA0 = tid >> 3;            // 0..63   (slot = tid)
    const int rowA1 = (tid + 512) >> 3;    // 64..127 (slot = tid+512)
    const int colA  = (tid & 7) * 8;
    // W staging: 512 slots, one per thread
    const int rowW  = tid >> 3;            // 0..63
    const int frg   = l15 * 72 + quad * 8; // fragment base (elements)

    // fused-combine A-chunk: head h = kt
    auto combineA = [&](int kt, bf16x8& a0out, bf16x8& a1out) {
        const float* p0 = po + ((size_t)kt * S_LEN + mb) * DH;
        const float* p1 = po + ((size_t)(NH + kt) * S_LEN + mb) * DH;
        const float* l0 = ls + (size_t)kt * S_LEN + mb;
        const float* l1 = ls + (size_t)(NH + kt) * S_LEN + mb;
        const float inv0 = 1.0f / (l0[rowA0] + l1[rowA0]);
        const float inv1 = 1.0f / (l0[rowA1] + l1[rowA1]);
        f32x4 xa0 = *(const f32x4*)(p0 + rowA0 * DH + colA);
        f32x4 xa1 = *(const f32x4*)(p0 + rowA0 * DH + colA + 4);
        f32x4 ya0 = *(const f32x4*)(p1 + rowA0 * DH + colA);
        f32x4 ya1 = *(const f32x4*)(p1 + rowA0 * DH + colA + 4);
        f32x4 xb0 = *(const f32x4*)(p0 + rowA1 * DH + colA);
        f32x4 xb1 = *(const f32x4*)(p0 + rowA1 * DH + colA + 4);
        f32x4 yb0 = *(const f32x4*)(p1 + rowA1 * DH + colA);
        f32x4 yb1 = *(const f32x4*)(p1 + rowA1 * DH + colA + 4);
#pragma unroll
        for (int e = 0; e < 4; ++e) {
            a0out[e]     = (bf16_t)((xa0[e] + ya0[e]) * inv0);
            a0out[4 + e] = (bf16_t)((xa1[e] + ya1[e]) * inv0);
            a1out[e]     = (bf16_t)((xb0[e] + yb0[e]) * inv1);
            a1out[4 + e] = (bf16_t)((xb1[e] + yb1[e]) * inv1);
        }
    };

    f32x4 acc[4];
#pragma unroll
    for (int nb = 0; nb < 4; ++nb) acc[nb] = (f32x4){0.f, 0.f, 0.f, 0.f};

    // prologue: stage chunk 0
    {
        bf16x8 a0, a1;
        combineA(0, a0, a1);
        bf16x8 w0 = *(const bf16x8*)(wb + (n0 + rowW) * NE + colA);
        *(bf16x8*)(abuf[0] + rowA0 * 72 + colA) = a0;
        *(bf16x8*)(abuf[0] + rowA1 * 72 + colA) = a1;
        *(bf16x8*)(wbuf[0] + rowW * 72 + colA) = w0;
    }
    __syncthreads();

    for (int kt = 0; kt < 16; ++kt) {
        const bf16_t* ab_ = abuf[kt & 1];
        const bf16_t* wb_ = wbuf[kt & 1];
        const bool pf = (kt + 1 < 16);
        bf16x8 an0, an1, wn;
        if (pf) {
            combineA(kt + 1, an0, an1);
            wn = *(const bf16x8*)(wb + (n0 + rowW) * NE + (kt + 1) * 64 + colA);
        }

        bf16x8 a0 = *(const bf16x8*)(ab_ + wave * (16 * 72) + frg);
        bf16x8 a1 = *(const bf16x8*)(ab_ + wave * (16 * 72) + frg + 32);
#pragma unroll
        for (int nb = 0; nb < 4; ++nb) {
            bf16x8 b0 = *(const bf16x8*)(wb_ + nb * (16 * 72) + frg);
            bf16x8 b1 = *(const bf16x8*)(wb_ + nb * (16 * 72) + frg + 32);
            acc[nb] = __builtin_amdgcn_mfma_f32_16x16x32_bf16(a0, b0, acc[nb], 0, 0, 0);
            acc[nb] = __builtin_amdgcn_mfma_f32_16x16x32_bf16(a1, b1, acc[nb], 0, 0, 0);
        }

        if (pf) {
            bf16_t* ad = abuf[(kt + 1) & 1];
            bf16_t* wd = wbuf[(kt + 1) & 1];
            *(bf16x8*)(ad + rowA0 * 72 + colA) = an0;
            *(bf16x8*)(ad + rowA1 * 72 + colA) = an1;
            *(bf16x8*)(wd + rowW * 72 + colA) = wn;
        }
        __syncthreads();
    }

#pragma unroll
    for (int nb = 0; nb < 4; ++nb)
#pragma unroll
        for (int r = 0; r < 4; ++r)
            y[(m0 + quad * 4 + r) * NE + n0 + nb * 16 + l15] = acc[nb][r];
}

extern "C" void kernel_launch(void* const* d_in, const int* in_sizes, int n_in,
                              void* d_out, int out_size, void* d_ws, size_t ws_size,
                              hipStream_t stream) {
    const float* q = (const float*)d_in[0];
    const float* k = (const float*)d_in[1];
    const float* v = (const float*)d_in[2];
    const float* w = (const float*)d_in[3];
    float* y = (float*)d_out;

    // ws: bf16 {qb 4M | kb 4M | vt 4M | wb 1M | xb 4M (unused)} then fp32
    // {po 8M | ls 128K}
    bf16_t* ws = (bf16_t*)d_ws;
    bf16_t* qb = ws;
    bf16_t* kb = qb + 4 * 1024 * 1024;
    bf16_t* vt = kb + 4 * 1024 * 1024;
    bf16_t* wb = vt + 4 * 1024 * 1024;
    bf16_t* xb = wb + 1024 * 1024;   // retained in layout; no longer written
    float*  po = (float*)(xb + 4 * 1024 * 1024);
    float*  ls = po + (size_t)2 * NH * S_LEN * DH;

    pack_all<<<dim3(4096 + 1024), dim3(256), 0, stream>>>(q, k, w, v, qb, kb, wb, vt);
    attn<<<dim3(NH, 32), dim3(512), 0, stream>>>(qb, kb, vt, po, ls);
    proj<<<dim3(S_LEN / 128, NE / 64), dim3(512), 0, stream>>>(po, ls, wb, y);
}

// Round 15
// 177.482 us; speedup vs baseline: 1.0228x; 1.0228x over previous
//
#include <hip/hip_runtime.h>

#define S_LEN 4096
#define NH 16
#define DH 64
#define NE 1024

typedef __bf16 bf16_t;
typedef __bf16 bf16x8 __attribute__((ext_vector_type(8)));
typedef __bf16 bf16x4 __attribute__((ext_vector_type(4)));
typedef __bf16 bf16x2 __attribute__((ext_vector_type(2)));
typedef float  f32x4  __attribute__((ext_vector_type(4)));

#define QSCALE 0.180336879f  // 0.125 * log2(e): softmax in exp2 domain

// ---------------------------------------------------------------------------
// Fused pack kernel. Blocks [0,4096): q,k -> head-major bf16 (q pre-scaled
// QSCALE) + W -> bf16. Blocks [4096,5120): V -> vt[h][d][t'] transpose with
// the within-64 key permutation (vt[pos] = V[ip(pos)]) so attn's PV
// B-fragment is one contiguous b128. Lanes write CONTIGUOUS vt addresses,
// read inverse-permuted LDS entries.
// ---------------------------------------------------------------------------
__global__ __launch_bounds__(256) void pack_all(const float* __restrict__ q,
                                                const float* __restrict__ k,
                                                const float* __restrict__ w,
                                                const float* __restrict__ v,
                                                bf16_t* __restrict__ qb,
                                                bf16_t* __restrict__ kb,
                                                bf16_t* __restrict__ wb,
                                                bf16_t* __restrict__ vt) {
    __shared__ bf16_t tile[64][65];
    const int bid = blockIdx.x;
    if (bid < 4096) {
        const int tid = bid * 256 + threadIdx.x;
        const int e = tid * 4;
        const int s = e >> 10;
        const int c = e & (NE - 1);
        const int h = c >> 6;
        const int d = c & (DH - 1);
        const int o = (h * S_LEN + s) * DH + d;
        float4 qv = *(const float4*)(q + e);
        float4 kv = *(const float4*)(k + e);
        bf16x4 qo, ko;
        qo[0] = (bf16_t)(qv.x * QSCALE); qo[1] = (bf16_t)(qv.y * QSCALE);
        qo[2] = (bf16_t)(qv.z * QSCALE); qo[3] = (bf16_t)(qv.w * QSCALE);
        ko[0] = (bf16_t)kv.x; ko[1] = (bf16_t)kv.y; ko[2] = (bf16_t)kv.z; ko[3] = (bf16_t)kv.w;
        *(bf16x4*)(qb + o) = qo;
        *(bf16x4*)(kb + o) = ko;
        if (tid < (NE * NE / 4)) {
            float4 wv = *(const float4*)(w + tid * 4);
            bf16x4 wo;
            wo[0] = (bf16_t)wv.x; wo[1] = (bf16_t)wv.y; wo[2] = (bf16_t)wv.z; wo[3] = (bf16_t)wv.w;
            *(bf16x4*)(wb + tid * 4) = wo;
        }
    } else {
        const int vb = bid - 4096;
        const int h  = vb >> 6;
        const int t0 = (vb & 63) * 64;
        const int r  = threadIdx.x >> 6;   // 0..3
        const int cl = threadIdx.x & 63;
#pragma unroll
        for (int rep = 0; rep < 16; ++rep) {
            int i = rep * 4 + r;
            tile[cl][i] = (bf16_t)v[(t0 + i) * NE + h * DH + cl];
        }
        __syncthreads();
        const int r2  = threadIdx.x >> 5;        // 0..7
        const int cl2 = (threadIdx.x & 31) * 2;  // 0..62 even
        // inverse key permutation: old = n5*32 + n2*16 + n4*8 + n3*4 + n1n0
        const int ip = (cl2 & 32) + ((cl2 >> 2) & 1) * 16 + ((cl2 >> 4) & 1) * 8 +
                       ((cl2 >> 3) & 1) * 4 + (cl2 & 3);
#pragma unroll
        for (int rep = 0; rep < 8; ++rep) {
            int d = rep * 8 + r2;
            bf16x2 out;
            out[0] = tile[d][ip];
            out[1] = tile[d][ip + 1];
            *(bf16x2*)(vt + (h * DH + d) * S_LEN + t0 + cl2) = out;
        }
    }
}

// ---------------------------------------------------------------------------
// Flash attention v19 (round-12/13 verbatim, 63 us measured): 4-slot LDS
// ring (1 barrier / 2 tiles), swapped QK^T (no P round-trip), pre-permuted
// V (single b128 PV B-frags), ones-MFMA row sums, raw v_exp_f32 softmax,
// hoisted per-chunk mask limit.
// ---------------------------------------------------------------------------
__global__ __launch_bounds__(512, 4) void attn(const bf16_t* __restrict__ qb,
                                               const bf16_t* __restrict__ kb,
                                               const bf16_t* __restrict__ vt,
                                               float* __restrict__ po,
                                               float* __restrict__ ls) {
    __shared__ __align__(16) bf16_t kbuf[4][64 * 72];
    __shared__ __align__(16) bf16_t vbuf[4][64 * 72];

    const int tid  = threadIdx.x;
    const int wave = tid >> 6;        // 0..7
    const int lane = tid & 63;
    const int l15  = lane & 15;
    const int quad = lane >> 4;
    const int h = blockIdx.x;
    const int x = blockIdx.y;

    const int sA = x;
    const int sB = 31 - x;
    const int n0 = x + 1;            // phase0 tile count
    const int b1 = sB + 1;           // phase1 first tile -> t0 base
    const int N  = 33;               // constant for all x

    const bf16_t* __restrict__ qh = qb + h * (S_LEN * DH);
    const bf16_t* __restrict__ kh = kb + h * (S_LEN * DH);
    const bf16_t* __restrict__ vh = vt + h * (DH * S_LEN);

    const int row0 = tid >> 3;        // 0..63
    const int tc8  = (tid & 7) * 8;   // 0..56
    const int stg  = row0 * 72 + tc8; // staging LDS offset (elements)
    const int frg  = l15 * 72 + quad * 8;  // fragment base offset (elements)

    f32x4 o_acc[4];
    f32x4 rs;                         // running row-sums via ones-MFMA
    bf16x8 qA[2];
    bf16x8 ones;
#pragma unroll
    for (int e = 0; e < 8; ++e) ones[e] = (bf16_t)1.0f;
    int s0 = sA * 128 + wave * 16;

    auto t0_of = [&](int j) { return (j < n0 ? j : b1 + (j - n0)) * 64; };

    auto load_q = [&](int s0_) {
#pragma unroll
        for (int dc = 0; dc < 2; ++dc)
            qA[dc] = *(const bf16x8*)(qh + (s0_ + l15) * DH + dc * 32 + quad * 8);
    };
    auto reset_acc = [&]() {
#pragma unroll
        for (int db = 0; db < 4; ++db) o_acc[db] = (f32x4){0.f, 0.f, 0.f, 0.f};
        rs = (f32x4){0.f, 0.f, 0.f, 0.f};
    };
    auto epilogue = [&](int s0_, int slot) {
        float* poz = po + (size_t)(slot * NH + h) * S_LEN * DH;
#pragma unroll
        for (int r = 0; r < 4; ++r)
#pragma unroll
            for (int db = 0; db < 4; ++db)
                poz[(s0_ + quad * 4 + r) * DH + db * 16 + l15] = o_acc[db][r];
        if (l15 == 0) {
            float* lsz = ls + (size_t)(slot * NH + h) * S_LEN;
#pragma unroll
            for (int r = 0; r < 4; ++r) lsz[s0_ + quad * 4 + r] = rs[r];
        }
    };

    load_q(s0);
    reset_acc();

    // prologue: stage tiles 0 and 1 into ring slots 0, 1
#pragma unroll
    for (int jj = 0; jj < 2; ++jj) {
        const int t0p = t0_of(jj);
        bf16x8 kr = *(const bf16x8*)(kh + (t0p + row0) * DH + tc8);
        bf16x8 vr = *(const bf16x8*)(vh + row0 * S_LEN + t0p + tc8);
        *(bf16x8*)(kbuf[jj] + stg) = kr;
        *(bf16x8*)(vbuf[jj] + stg) = vr;
    }
    __syncthreads();

    bf16x8 krn[2], vrn[2];            // prefetch regs for the next pair

#pragma unroll 2
    for (int j = 0; j < N; ++j) {
        if (j == n0) {  // phase switch (block-uniform)
            epilogue(s0, 0);
            s0 = sB * 128 + wave * 16;
            load_q(s0);
            reset_acc();
        }
        const int t0 = t0_of(j);
        const bf16_t* kb_ = kbuf[j & 3];
        const bf16_t* vb_ = vbuf[j & 3];

        if ((j & 1) == 0) {
            // pair start: issue global loads for tiles j+2, j+3 (uniform guards)
#pragma unroll
            for (int u = 0; u < 2; ++u) {
                const int jn = j + 2 + u;
                if (jn < N) {
                    const int tn = t0_of(jn);
                    krn[u] = *(const bf16x8*)(kh + (tn + row0) * DH + tc8);
                    vrn[u] = *(const bf16x8*)(vh + row0 * S_LEN + tn + tc8);
                }
            }
        }

        // wave-uniform: this tile contributes only if some key <= some query
        if (t0 <= s0 + 15) {
            // ---- swapped QK^T: A = K fragments, B = Q (in registers)
            f32x4 c_[4];
#pragma unroll
            for (int ch = 0; ch < 4; ++ch) {
                bf16x8 kB0 = *(const bf16x8*)(kb_ + frg + ch * (16 * 72));
                bf16x8 kB1 = *(const bf16x8*)(kb_ + frg + ch * (16 * 72) + 32);
                f32x4 zr = (f32x4){0.f, 0.f, 0.f, 0.f};
                zr = __builtin_amdgcn_mfma_f32_16x16x32_bf16(kB0, qA[0], zr, 0, 0, 0);
                zr = __builtin_amdgcn_mfma_f32_16x16x32_bf16(kB1, qA[1], zr, 0, 0, 0);
                c_[ch] = zr;
            }

            // ---- mask + exp2 + lane-local pack into PV A-fragments
            // lane holds S^T[key=t0+16ch+4quad+r][query=s0+l15].
            // Mask limit hoisted: element (ch,r) masked iff r > lim(ch).
            const int query = s0 + l15;
            float p[4][4];
#pragma unroll
            for (int ch = 0; ch < 4; ++ch) {
                if (t0 + ch * 16 <= s0 + 15) {       // wave-uniform chunk-live
                    const bool edge = (t0 + ch * 16 + 15 > s0);
                    const int lim = query - (t0 + ch * 16 + quad * 4);
#pragma unroll
                    for (int r = 0; r < 4; ++r) {
                        float cc = c_[ch][r];
                        if (edge && r > lim) cc = -INFINITY;
                        p[ch][r] = __builtin_amdgcn_exp2f(cc);
                    }
                } else {
#pragma unroll
                    for (int r = 0; r < 4; ++r) p[ch][r] = 0.0f;
                }
            }

            bf16x8 pA[2];
#pragma unroll
            for (int kc = 0; kc < 2; ++kc) {
                bf16x8 t;
                t[0] = (bf16_t)p[2 * kc][0];     t[1] = (bf16_t)p[2 * kc][1];
                t[2] = (bf16_t)p[2 * kc][2];     t[3] = (bf16_t)p[2 * kc][3];
                t[4] = (bf16_t)p[2 * kc + 1][0]; t[5] = (bf16_t)p[2 * kc + 1][1];
                t[6] = (bf16_t)p[2 * kc + 1][2]; t[7] = (bf16_t)p[2 * kc + 1][3];
                pA[kc] = t;
            }

            // ---- row-sums on the matrix pipe (replaces 16 VALU adds)
            rs = __builtin_amdgcn_mfma_f32_16x16x32_bf16(pA[0], ones, rs, 0, 0, 0);
            rs = __builtin_amdgcn_mfma_f32_16x16x32_bf16(pA[1], ones, rs, 0, 0, 0);

            // ---- PV: V pre-permuted -> single uniform b128 per fragment
#pragma unroll
            for (int db = 0; db < 4; ++db) {
#pragma unroll
                for (int kc = 0; kc < 2; ++kc) {
                    bf16x8 vB = *(const bf16x8*)(vb_ + frg + db * (16 * 72) + kc * 32);
                    o_acc[db] = __builtin_amdgcn_mfma_f32_16x16x32_bf16(pA[kc], vB, o_acc[db], 0, 0, 0);
                }
            }
        }

        if (j & 1) {
            // pair end: commit staged tiles j+1, j+2 to their ring slots,
            // then ONE barrier for the pair.
#pragma unroll
            for (int u = 0; u < 2; ++u) {
                const int jn = j + 1 + u;
                if (jn < N) {
                    *(bf16x8*)(kbuf[jn & 3] + stg) = krn[u];
                    *(bf16x8*)(vbuf[jn & 3] + stg) = vrn[u];
                }
            }
            __syncthreads();
        }
    }

    epilogue(s0, 1);
}

// ---------------------------------------------------------------------------
// Combine (standalone, restored — round-14 fusion into proj cost +3.7 us
// from 16x redundant per-n-block combine work): xb[row][h*64+d] =
// (o0 + o1) / (l0 + l1), fp32 partials -> bf16.
// ---------------------------------------------------------------------------
__global__ __launch_bounds__(256) void combine(const float* __restrict__ po,
                                               const float* __restrict__ ls,
                                               bf16_t* __restrict__ xb) {
    const int idx = blockIdx.x * 256 + threadIdx.x;
    const int row = idx >> 8;
    const int c   = (idx & 255) * 4;
    const int h   = c >> 6;
    const int d   = c & 63;
    const size_t base0 = (size_t)(h) * S_LEN * DH + row * DH + d;
    const size_t base1 = (size_t)(NH + h) * S_LEN * DH + row * DH + d;
    float4 o0 = *(const float4*)(po + base0);
    float4 o1 = *(const float4*)(po + base1);
    float l = ls[(size_t)h * S_LEN + row] + ls[(size_t)(NH + h) * S_LEN + row];
    float inv = 1.0f / l;
    bf16x4 out;
    out[0] = (bf16_t)((o0.x + o1.x) * inv);
    out[1] = (bf16_t)((o0.y + o1.y) * inv);
    out[2] = (bf16_t)((o0.z + o1.z) * inv);
    out[3] = (bf16_t)((o0.w + o1.w) * inv);
    *(bf16x4*)(xb + (size_t)row * NE + c) = out;
}

// ---------------------------------------------------------------------------
// Projection v10 (round-13 verbatim): Y[4096][1024] = X(bf16) @ W^T(bf16),
// fp32 out. Canonical both-staged GEMM: A-panel (128x64/chunk) and W-panel
// (64x64/chunk) staged via fully-coalesced 128B global runs, read back as
// the stride-72 ds_read_b128 pattern. 512 threads = 8 waves x m16; BM=128
// BN=64; grid (32,16); LDS 55296B -> 2 blocks/CU = 16 waves/CU. Double-
// buffered, one sync per chunk.
// ---------------------------------------------------------------------------
__global__ __launch_bounds__(512, 2) void proj(const bf16_t* __restrict__ xb,
                                               const bf16_t* __restrict__ wb,
                                               float* __restrict__ y) {
    __shared__ __align__(16) bf16_t abuf[2][128 * 72];
    __shared__ __align__(16) bf16_t wbuf[2][64 * 72];
    const int tid  = threadIdx.x;
    const int wave = tid >> 6;        // 0..7
    const int lane = tid & 63;
    const int l15  = lane & 15;
    const int quad = lane >> 4;
    const int mb = blockIdx.x * 128;  // block row base
    const int m0 = mb + wave * 16;    // wave owns 16 rows
    const int n0 = blockIdx.y * 64;

    // A staging: 1024 slots of 8 elts; thread covers slots tid, tid+512
    const int rowA0 = tid >> 3;            // 0..63   (slot = tid)
    const int rowA1 = (tid + 512) >> 3;    // 64..127 (slot = tid+512)
    const int colA  = (tid & 7) * 8;
    // W staging: 512 slots, one per thread
    const int rowW  = tid >> 3;            // 0..63
    const int frg   = l15 * 72 + quad * 8; // fragment base (elements)

    f32x4 acc[4];
#pragma unroll
    for (int nb = 0; nb < 4; ++nb) acc[nb] = (f32x4){0.f, 0.f, 0.f, 0.f};

    // prologue: stage chunk 0
    {
        bf16x8 a0 = *(const bf16x8*)(xb + (mb + rowA0) * NE + colA);
        bf16x8 a1 = *(const bf16x8*)(xb + (mb + rowA1) * NE + colA);
        bf16x8 w0 = *(const bf16x8*)(wb + (n0 + rowW) * NE + colA);
        *(bf16x8*)(abuf[0] + rowA0 * 72 + colA) = a0;
        *(bf16x8*)(abuf[0] + rowA1 * 72 + colA) = a1;
        *(bf16x8*)(wbuf[0] + rowW * 72 + colA) = w0;
    }
    __syncthreads();

    for (int kt = 0; kt < 16; ++kt) {
        const bf16_t* ab_ = abuf[kt & 1];
        const bf16_t* wb_ = wbuf[kt & 1];
        const bool pf = (kt + 1 < 16);
        bf16x8 an0, an1, wn;
        if (pf) {
            const int kn = (kt + 1) * 64;
            an0 = *(const bf16x8*)(xb + (mb + rowA0) * NE + kn + colA);
            an1 = *(const bf16x8*)(xb + (mb + rowA1) * NE + kn + colA);
            wn  = *(const bf16x8*)(wb + (n0 + rowW) * NE + kn + colA);
        }

        bf16x8 a0 = *(const bf16x8*)(ab_ + wave * (16 * 72) + frg);
        bf16x8 a1 = *(const bf16x8*)(ab_ + wave * (16 * 72) + frg + 32);
#pragma unroll
        for (int nb = 0; nb < 4; ++nb) {
            bf16x8 b0 = *(const bf16x8*)(wb_ + nb * (16 * 72) + frg);
            bf16x8 b1 = *(const bf16x8*)(wb_ + nb * (16 * 72) + frg + 32);
            acc[nb] = __builtin_amdgcn_mfma_f32_16x16x32_bf16(a0, b0, acc[nb], 0, 0, 0);
            acc[nb] = __builtin_amdgcn_mfma_f32_16x16x32_bf16(a1, b1, acc[nb], 0, 0, 0);
        }

        if (pf) {
            bf16_t* ad = abuf[(kt + 1) & 1];
            bf16_t* wd = wbuf[(kt + 1) & 1];
            *(bf16x8*)(ad + rowA0 * 72 + colA) = an0;
            *(bf16x8*)(ad + rowA1 * 72 + colA) = an1;
            *(bf16x8*)(wd + rowW * 72 + colA) = wn;
        }
        __syncthreads();
    }

#pragma unroll
    for (int nb = 0; nb < 4; ++nb)
#pragma unroll
        for (int r = 0; r < 4; ++r)
            y[(m0 + quad * 4 + r) * NE + n0 + nb * 16 + l15] = acc[nb][r];
}

extern "C" void kernel_launch(void* const* d_in, const int* in_sizes, int n_in,
                              void* d_out, int out_size, void* d_ws, size_t ws_size,
                              hipStream_t stream) {
    const float* q = (const float*)d_in[0];
    const float* k = (const float*)d_in[1];
    const float* v = (const float*)d_in[2];
    const float* w = (const float*)d_in[3];
    float* y = (float*)d_out;

    // ws: bf16 {qb 4M | kb 4M | vt 4M | wb 1M | xb 4M} then fp32 {po 8M | ls 128K}
    bf16_t* ws = (bf16_t*)d_ws;
    bf16_t* qb = ws;
    bf16_t* kb = qb + 4 * 1024 * 1024;
    bf16_t* vt = kb + 4 * 1024 * 1024;
    bf16_t* wb = vt + 4 * 1024 * 1024;
    bf16_t* xb = wb + 1024 * 1024;
    float*  po = (float*)(xb + 4 * 1024 * 1024);
    float*  ls = po + (size_t)2 * NH * S_LEN * DH;

    pack_all<<<dim3(4096 + 1024), dim3(256), 0, stream>>>(q, k, w, v, qb, kb, wb, vt);
    attn<<<dim3(NH, 32), dim3(512), 0, stream>>>(qb, kb, vt, po, ls);
    combine<<<dim3(4096), dim3(256), 0, stream>>>(po, ls, xb);
    proj<<<dim3(S_LEN / 128, NE / 64), dim3(512), 0, stream>>>(xb, wb, y);
}